// Round 13
// baseline (183.899 us; speedup 1.0000x reference)
//
#include <hip/hip_runtime.h>
#include <hip/hip_bf16.h>

typedef unsigned short u16;
typedef __attribute__((ext_vector_type(4))) int   i32x4;
typedef __attribute__((ext_vector_type(4))) float f32x4;

constexpr int N = 8192;
constexpr int D = 1024;
constexpr float INVT = 1.0f / 0.07f;
constexpr int KT = 16;                         // K-tiles (BK=64 i8)
constexpr int NBLK = 64;
constexpr int NTRI = NBLK * (NBLK + 1) / 2;    // 2080 lower-tri tiles
constexpr int PANEL_BYTES = 128 * 1024;

// ---- workspace layout (bytes) ----
constexpr size_t OFF_Q8    = 0;                      // 8 MiB tiled q8
constexpr size_t OFF_SUME  = 8388608;                // N f32
constexpr size_t OFF_POSS  = OFF_SUME + 32768;       // N f32
constexpr size_t OFF_TYPE  = OFF_POSS + 32768;       // N i32
constexpr size_t OFF_SCALE = OFF_TYPE + 32768;       // N f32
constexpr size_t OFF_SESCR = OFF_SCALE + 32768;      // N f32 (ablation)
constexpr size_t OFF_PSSCR = OFF_SESCR + 32768;      // N f32 (ablation)
constexpr size_t OFF_STORE = OFF_PSSCR + 32768;      // 2080*256 f32 (ablation)

__global__ __launch_bounds__(256) void k_norm(
    const float* __restrict__ feat, const long long* __restrict__ et,
    signed char* __restrict__ q8, float* __restrict__ scales,
    int* __restrict__ types, float* __restrict__ sum_exp,
    float* __restrict__ pos_sum, float* __restrict__ se_scr,
    float* __restrict__ ps_scr) {
  const int t = threadIdx.x;
  if      (t < 4)  sum_exp[blockIdx.x * 4 + t] = 0.f;
  else if (t < 8)  pos_sum[blockIdx.x * 4 + t - 4] = 0.f;
  else if (t < 12) se_scr [blockIdx.x * 4 + t - 8] = 0.f;
  else if (t < 16) ps_scr [blockIdx.x * 4 + t - 12] = 0.f;

  const int row = blockIdx.x * 4 + (t >> 6);
  const int l = t & 63;
  const float4* src = (const float4*)(feat + (size_t)row * D);
  float4 v[4];
  float ss = 0.f, ma = 0.f;
  #pragma unroll
  for (int c = 0; c < 4; ++c) {
    v[c] = src[c * 64 + l];
    ss += v[c].x * v[c].x + v[c].y * v[c].y + v[c].z * v[c].z + v[c].w * v[c].w;
    ma = fmaxf(ma, fmaxf(fmaxf(fabsf(v[c].x), fabsf(v[c].y)),
                         fmaxf(fabsf(v[c].z), fabsf(v[c].w))));
  }
  #pragma unroll
  for (int m = 32; m; m >>= 1) {
    ss += __shfl_xor(ss, m);
    ma = fmaxf(ma, __shfl_xor(ma, m));
  }
  const float sc = 1.0f / fmaxf(sqrtf(ss), 1e-12f);
  const float man = ma * sc;
  const float invq = 127.0f / fmaxf(man, 1e-30f);
  const float qf = sc * invq;
  signed char* pb = q8 + (size_t)(row >> 7) * PANEL_BYTES + (row & 127) * 16;
  #pragma unroll
  for (int c = 0; c < 4; ++c) {
    const int b0 = (unsigned char)(signed char)__float2int_rn(v[c].x * qf);
    const int b1 = (unsigned char)(signed char)__float2int_rn(v[c].y * qf);
    const int b2 = (unsigned char)(signed char)__float2int_rn(v[c].z * qf);
    const int b3 = (unsigned char)(signed char)__float2int_rn(v[c].w * qf);
    const int w = c * 64 + l;
    *(int*)(pb + (w >> 2) * 2048 + (w & 3) * 4) =
        b0 | (b1 << 8) | (b2 << 16) | (b3 << 24);
  }
  if (l == 0) {
    scales[row] = man / 127.0f;
    types[row] = (int)et[row];
  }
}

__device__ __forceinline__ void mfma_i8v(i32x4& d, i32x4 a, i32x4 b) {
  asm volatile("v_mfma_i32_16x16x64_i8 %0, %1, %2, %0"
               : "+v"(d) : "v"(a), "v"(b));
}

// ABLATION round. MODE 0 = full (real outputs). MODE 1 = K-loop only
// (epilogue replaced by DCE-proof plain store). MODE 2 = epilogue only
// (K-loop skipped, acc=0, atomics at scratch with identical address
// pattern). Per-dispatch rocprof dur localizes the ~100us.
template <int MODE>
__global__ __launch_bounds__(256) void k_gemm(
    const signed char* __restrict__ q8, const float* __restrict__ scales,
    const int* __restrict__ types,
    float* __restrict__ se_t, float* __restrict__ ps_t,
    float* __restrict__ store_scr) {
  __shared__ int rt[128], ct[128];
  __shared__ float rsl[128], csl[128];

  // chunked Latin-square XCD tile decode (r12)
  const int pid = blockIdx.x;
  const int x = pid & 7;
  int l = pid >> 3;
  int b = 0, p = 0;
  for (;;) {
    p = (b + x) & 7;
    const int nb = 8 * b + 8 - p;
    if (l < nb) break;
    l -= nb; ++b;
  }
  int j = 0;
  for (;;) {
    const int cnt = (j == b) ? (8 - p) : 8;
    if (l < cnt) break;
    l -= cnt; ++j;
  }
  const int cb = 8 * j + ((j + x) & 7);
  const int rb = 8 * b + ((j == b) ? (p + l) : l);

  const int brow = rb * 128, bcol = cb * 128;
  const bool diag = (rb == cb);

  const int tid = threadIdx.x;
  const int lane = tid & 63;
  const int wid = tid >> 6;
  const int wr = wid >> 1, wc = wid & 1;

  if (tid < 128) {
    rt[tid] = types[brow + tid];
    rsl[tid] = scales[brow + tid] * INVT;
  } else {
    ct[tid - 128] = types[bcol + tid - 128];
    csl[tid - 128] = scales[bcol + tid - 128];
  }
  __syncthreads();

  i32x4 acc[4][4];
  #pragma unroll
  for (int i = 0; i < 4; ++i)
    #pragma unroll
    for (int jj = 0; jj < 4; ++jj) acc[i][jj] = (i32x4){0, 0, 0, 0};

  const int slotR = lane >> 4;
  const int arow = wr * 64 + (lane & 15);
  const int brw  = wc * 64 + (lane & 15);
  const signed char* pA =
      q8 + (size_t)rb * PANEL_BYTES + (slotR * 128 + arow) * 16;
  const signed char* pB =
      q8 + (size_t)cb * PANEL_BYTES + (slotR * 128 + brw) * 16;

  i32x4 a0[4], b0[4], a1[4], b1[4];

  #define LOADP(tt, A, B) {                                           \
    const int o = (tt) * 8192;                                        \
    _Pragma("unroll")                                                 \
    for (int q = 0; q < 4; ++q) {                                     \
      A[q] = *(const i32x4*)(pA + o + q * 256);                       \
      B[q] = *(const i32x4*)(pB + o + q * 256);                       \
    } }

  #define MFMAP(A, B) {                                               \
    __builtin_amdgcn_s_setprio(1);                                    \
    _Pragma("unroll")                                                 \
    for (int mi = 0; mi < 4; ++mi)                                    \
      _Pragma("unroll")                                               \
      for (int ni = 0; ni < 4; ++ni) mfma_i8v(acc[mi][ni], A[mi], B[ni]); \
    __builtin_amdgcn_s_setprio(0);                                    \
  }

  if constexpr (MODE != 2) {
    LOADP(0, a0, b0)
    LOADP(1, a1, b1)
    for (int t = 0; t < KT; t += 2) {
      MFMAP(a0, b0)
      if (t + 2 < KT) LOADP(t + 2, a0, b0)
      MFMAP(a1, b1)
      if (t + 3 < KT) LOADP(t + 3, a1, b1)
    }
    asm volatile("s_nop 7\n\ts_nop 7\n\ts_nop 7");
    #pragma unroll
    for (int i = 0; i < 4; ++i)
      #pragma unroll
      for (int jj = 0; jj < 4; ++jj) asm volatile("" : "+v"(acc[i][jj]));
  }

  if constexpr (MODE == 1) {
    // keep the K-loop live without the epilogue: plain store of acc sum
    int keep = 0;
    #pragma unroll
    for (int i = 0; i < 4; ++i)
      #pragma unroll
      for (int jj = 0; jj < 4; ++jj)
        keep += acc[i][jj][0] + acc[i][jj][1] + acc[i][jj][2] + acc[i][jj][3];
    store_scr[(size_t)blockIdx.x * 256 + tid] = (float)keep;
    return;
  }

  // epilogue (MODE 0 real, MODE 2 ablation -> scratch targets)
  const int csub = lane & 15;
  const int rsub = (lane >> 4) * 4;
  int gcolv[4], ctv[4];
  float cfv[4];
  #pragma unroll
  for (int ni = 0; ni < 4; ++ni) {
    const int cl = wc * 64 + ni * 16 + csub;
    gcolv[ni] = bcol + cl;
    ctv[ni] = ct[cl];
    cfv[ni] = csl[cl];
  }
  float cse[4] = {0.f, 0.f, 0.f, 0.f};
  float cps[4] = {0.f, 0.f, 0.f, 0.f};

  #pragma unroll
  for (int mi = 0; mi < 4; ++mi) {
    #pragma unroll
    for (int r = 0; r < 4; ++r) {
      const int rl = wr * 64 + mi * 16 + rsub + r;
      const int grow = brow + rl;
      const int rty = rt[rl];
      const float rfac = rsl[rl];
      float se = 0.f, ps = 0.f;
      #pragma unroll
      for (int ni = 0; ni < 4; ++ni) {
        const float s = (float)acc[mi][ni][r] * rfac * cfv[ni];
        const float e = __expf(s);
        const bool match = (ctv[ni] == rty);
        if (diag) {
          if (gcolv[ni] != grow) { se += e; if (match) ps += s; }
        } else {
          se += e; if (match) ps += s;
          cse[ni] += e; if (match) cps[ni] += s;
        }
      }
      #pragma unroll
      for (int m = 8; m; m >>= 1) {
        se += __shfl_xor(se, m);
        ps += __shfl_xor(ps, m);
      }
      if (csub == 0) {
        atomicAdd(&se_t[grow], se);
        atomicAdd(&ps_t[grow], ps);
      }
    }
  }

  if (!diag) {
    #pragma unroll
    for (int ni = 0; ni < 4; ++ni) {
      float se = cse[ni], ps = cps[ni];
      se += __shfl_xor(se, 16); se += __shfl_xor(se, 32);
      ps += __shfl_xor(ps, 16); ps += __shfl_xor(ps, 32);
      if (lane < 16) {
        atomicAdd(&se_t[gcolv[ni]], se);
        atomicAdd(&ps_t[gcolv[ni]], ps);
      }
    }
  }
}

__global__ __launch_bounds__(1024) void k_final(
    const float* __restrict__ sum_exp, const float* __restrict__ pos_sum,
    const int* __restrict__ types, float* __restrict__ out) {
  const int t = threadIdx.x;
  __shared__ int h[32];
  if (t < 32) h[t] = 0;
  __syncthreads();
  int ty[8];
  #pragma unroll
  for (int i = 0; i < 8; ++i) {
    ty[i] = types[t + i * 1024];
    atomicAdd(&h[ty[i]], 1);
  }
  __syncthreads();
  float ls = 0.f, cnt = 0.f;
  #pragma unroll
  for (int i = 0; i < 8; ++i) {
    const int r = t + i * 1024;
    const int pc = h[ty[i]] - 1;
    if (pc > 0) {
      const float pm = pos_sum[r] / (float)pc;
      ls += -logf(__expf(pm) / sum_exp[r] + 1e-10f);
      cnt += 1.f;
    }
  }
  #pragma unroll
  for (int m = 32; m; m >>= 1) {
    ls += __shfl_xor(ls, m);
    cnt += __shfl_xor(cnt, m);
  }
  __shared__ float s1[16], s2[16];
  if ((t & 63) == 0) { s1[t >> 6] = ls; s2[t >> 6] = cnt; }
  __syncthreads();
  if (t == 0) {
    float T = 0.f, C = 0.f;
    for (int i = 0; i < 16; ++i) { T += s1[i]; C += s2[i]; }
    out[0] = (C > 0.f) ? T / C : 0.f;
  }
}

extern "C" void kernel_launch(void* const* d_in, const int* in_sizes, int n_in,
                              void* d_out, int out_size, void* d_ws, size_t ws_size,
                              hipStream_t stream) {
  const float* feat = (const float*)d_in[0];
  const long long* et = (const long long*)d_in[1];
  char* ws = (char*)d_ws;
  signed char* q8 = (signed char*)(ws + OFF_Q8);
  float* sum_e  = (float*)(ws + OFF_SUME);
  float* pos_s  = (float*)(ws + OFF_POSS);
  int* types    = (int*)(ws + OFF_TYPE);
  float* scale  = (float*)(ws + OFF_SCALE);
  float* se_scr = (float*)(ws + OFF_SESCR);
  float* ps_scr = (float*)(ws + OFF_PSSCR);
  float* st_scr = (float*)(ws + OFF_STORE);
  float* out    = (float*)d_out;

  k_norm<<<N / 4, 256, 0, stream>>>(feat, et, q8, scale, types,
                                    sum_e, pos_s, se_scr, ps_scr);
  // D_full: real result, runs first (cache conditions match prior rounds)
  k_gemm<0><<<NTRI, 256, 0, stream>>>(q8, scale, types, sum_e, pos_s, st_scr);
  // D_K: K-loop only (plain-store epilogue)
  k_gemm<1><<<NTRI, 256, 0, stream>>>(q8, scale, types, se_scr, ps_scr, st_scr);
  // D_EPI: epilogue only (acc = 0), atomics at scratch
  k_gemm<2><<<NTRI, 256, 0, stream>>>(q8, scale, types, se_scr, ps_scr, st_scr);
  k_final<<<1, 1024, 0, stream>>>(sum_e, pos_s, types, out);
}

// Round 14
// 83.900 us; speedup vs baseline: 2.1919x; 2.1919x over previous
//
#include <hip/hip_runtime.h>
#include <hip/hip_bf16.h>

typedef unsigned short u16;
typedef __attribute__((ext_vector_type(4))) int   i32x4;
typedef __attribute__((ext_vector_type(4))) float f32x4;

constexpr int N = 8192;
constexpr int D = 1024;
constexpr float INVT = 1.0f / 0.07f;
constexpr int KT = 16;                         // K-tiles (BK=64 i8)
constexpr int NBLK = 64;
constexpr int NTRI = NBLK * (NBLK + 1) / 2;    // 2080 lower-tri tiles
constexpr int PANEL_BYTES = 128 * 1024;

// ---- workspace layout (bytes) ----
constexpr size_t OFF_Q8    = 0;                        // 8 MiB tiled q8
constexpr size_t OFF_PSE   = 8388608;                  // 2080*256 f32 partials
constexpr size_t OFF_PPS   = OFF_PSE + 2129920;        // 2080*256 f32
constexpr size_t OFF_SUME  = OFF_PPS + 2129920;        // N f32
constexpr size_t OFF_POSS  = OFF_SUME + 32768;         // N f32
constexpr size_t OFF_TYPE  = OFF_POSS + 32768;         // N i32
constexpr size_t OFF_SCALE = OFF_TYPE + 32768;         // N f32

// one wave per row: normalize, per-row absmax, quantize to i8 into the
// TILED q8 layout (panel p, slot s, row r: byte = p*131072+s*2048+r*16).
__global__ __launch_bounds__(256) void k_norm(
    const float* __restrict__ feat, const long long* __restrict__ et,
    signed char* __restrict__ q8, float* __restrict__ scales,
    int* __restrict__ types) {
  const int t = threadIdx.x;
  const int row = blockIdx.x * 4 + (t >> 6);
  const int l = t & 63;
  const float4* src = (const float4*)(feat + (size_t)row * D);
  float4 v[4];
  float ss = 0.f, ma = 0.f;
  #pragma unroll
  for (int c = 0; c < 4; ++c) {
    v[c] = src[c * 64 + l];
    ss += v[c].x * v[c].x + v[c].y * v[c].y + v[c].z * v[c].z + v[c].w * v[c].w;
    ma = fmaxf(ma, fmaxf(fmaxf(fabsf(v[c].x), fabsf(v[c].y)),
                         fmaxf(fabsf(v[c].z), fabsf(v[c].w))));
  }
  #pragma unroll
  for (int m = 32; m; m >>= 1) {
    ss += __shfl_xor(ss, m);
    ma = fmaxf(ma, __shfl_xor(ma, m));
  }
  const float sc = 1.0f / fmaxf(sqrtf(ss), 1e-12f);
  const float man = ma * sc;
  const float invq = 127.0f / fmaxf(man, 1e-30f);
  const float qf = sc * invq;
  signed char* pb = q8 + (size_t)(row >> 7) * PANEL_BYTES + (row & 127) * 16;
  #pragma unroll
  for (int c = 0; c < 4; ++c) {
    const int b0 = (unsigned char)(signed char)__float2int_rn(v[c].x * qf);
    const int b1 = (unsigned char)(signed char)__float2int_rn(v[c].y * qf);
    const int b2 = (unsigned char)(signed char)__float2int_rn(v[c].z * qf);
    const int b3 = (unsigned char)(signed char)__float2int_rn(v[c].w * qf);
    const int w = c * 64 + l;
    *(int*)(pb + (w >> 2) * 2048 + (w & 3) * 4) =
        b0 | (b1 << 8) | (b2 << 16) | (b3 << 24);
  }
  if (l == 0) {
    scales[row] = man / 127.0f;
    types[row] = (int)et[row];
  }
}

__device__ __forceinline__ void mfma_i8v(i32x4& d, i32x4 a, i32x4 b) {
  asm volatile("v_mfma_i32_16x16x64_i8 %0, %1, %2, %0"
               : "+v"(d) : "v"(a), "v"(b));
}

// 128x128 lower-tri tiles of sim = (q8 . q8^T) * s_i * s_j / T.
// r12's barrier-free register K-loop + chunked XCD mapping, with the
// GLOBAL ATOMICS REMOVED: r13's WRITE_SIZE (20.6MB vs 64KB logical, a
// ~300x atomic write-through amplification; 2.1M device-scope atomicAdds
// onto 16K words) identified memory-side atomic serialization as the
// K-loop-invariant ~100us wall. Now: shuffle-reduce -> LDS atomicAdd
// into per-block slabs -> ONE coalesced 512-f32 plain store per block
// into partial[canonical_tile][256] (rows 0..127, cols 128..255).
// k_reduce gathers partials into sum_exp/pos_sum (no atomics anywhere).
__global__ __launch_bounds__(256) void k_gemm(
    const signed char* __restrict__ q8, const float* __restrict__ scales,
    const int* __restrict__ types,
    float* __restrict__ pse, float* __restrict__ pps) {
  __shared__ int rt[128], ct[128];
  __shared__ float rsl[128], csl[128];
  __shared__ float s_se[128], s_ps[128], s_cse[128], s_cps[128];

  // chunked Latin-square XCD tile decode (r12)
  const int pid = blockIdx.x;
  const int x = pid & 7;
  int l = pid >> 3;
  int b = 0, p = 0;
  for (;;) {
    p = (b + x) & 7;
    const int nb = 8 * b + 8 - p;
    if (l < nb) break;
    l -= nb; ++b;
  }
  int j = 0;
  for (;;) {
    const int cnt = (j == b) ? (8 - p) : 8;
    if (l < cnt) break;
    l -= cnt; ++j;
  }
  const int cb = 8 * j + ((j + x) & 7);
  const int rb = 8 * b + ((j == b) ? (p + l) : l);

  const int brow = rb * 128, bcol = cb * 128;
  const bool diag = (rb == cb);

  const int tid = threadIdx.x;
  const int lane = tid & 63;
  const int wid = tid >> 6;
  const int wr = wid >> 1, wc = wid & 1;

  if (tid < 128) {
    rt[tid] = types[brow + tid];
    rsl[tid] = scales[brow + tid] * INVT;
    s_se[tid] = 0.f; s_ps[tid] = 0.f;
  } else {
    ct[tid - 128] = types[bcol + tid - 128];
    csl[tid - 128] = scales[bcol + tid - 128];
    s_cse[tid - 128] = 0.f; s_cps[tid - 128] = 0.f;
  }
  __syncthreads();

  i32x4 acc[4][4];
  #pragma unroll
  for (int i = 0; i < 4; ++i)
    #pragma unroll
    for (int jj = 0; jj < 4; ++jj) acc[i][jj] = (i32x4){0, 0, 0, 0};

  const int slotR = lane >> 4;
  const int arow = wr * 64 + (lane & 15);
  const int brw  = wc * 64 + (lane & 15);
  const signed char* pA =
      q8 + (size_t)rb * PANEL_BYTES + (slotR * 128 + arow) * 16;
  const signed char* pB =
      q8 + (size_t)cb * PANEL_BYTES + (slotR * 128 + brw) * 16;

  i32x4 a0[4], b0[4], a1[4], b1[4];

  #define LOADP(tt, A, B) {                                           \
    const int o = (tt) * 8192;                                        \
    _Pragma("unroll")                                                 \
    for (int q = 0; q < 4; ++q) {                                     \
      A[q] = *(const i32x4*)(pA + o + q * 256);                       \
      B[q] = *(const i32x4*)(pB + o + q * 256);                       \
    } }

  #define MFMAP(A, B) {                                               \
    __builtin_amdgcn_s_setprio(1);                                    \
    _Pragma("unroll")                                                 \
    for (int mi = 0; mi < 4; ++mi)                                    \
      _Pragma("unroll")                                               \
      for (int ni = 0; ni < 4; ++ni) mfma_i8v(acc[mi][ni], A[mi], B[ni]); \
    __builtin_amdgcn_s_setprio(0);                                    \
  }

  LOADP(0, a0, b0)
  LOADP(1, a1, b1)
  for (int t = 0; t < KT; t += 2) {
    MFMAP(a0, b0)
    if (t + 2 < KT) LOADP(t + 2, a0, b0)
    MFMAP(a1, b1)
    if (t + 3 < KT) LOADP(t + 3, a1, b1)
  }

  // MFMA -> VALU read hazard guard
  asm volatile("s_nop 7\n\ts_nop 7\n\ts_nop 7");
  #pragma unroll
  for (int i = 0; i < 4; ++i)
    #pragma unroll
    for (int jj = 0; jj < 4; ++jj) asm volatile("" : "+v"(acc[i][jj]));

  // epilogue: C/D layout col = lane&15, row = (lane>>4)*4 + reg  [m89]
  const int csub = lane & 15;
  const int rsub = (lane >> 4) * 4;
  int gcolv[4], ctv[4];
  float cfv[4];
  #pragma unroll
  for (int ni = 0; ni < 4; ++ni) {
    const int cl = wc * 64 + ni * 16 + csub;
    gcolv[ni] = bcol + cl;
    ctv[ni] = ct[cl];
    cfv[ni] = csl[cl];
  }
  float cse[4] = {0.f, 0.f, 0.f, 0.f};
  float cps[4] = {0.f, 0.f, 0.f, 0.f};

  #pragma unroll
  for (int mi = 0; mi < 4; ++mi) {
    #pragma unroll
    for (int r = 0; r < 4; ++r) {
      const int rl = wr * 64 + mi * 16 + rsub + r;
      const int grow = brow + rl;
      const int rty = rt[rl];
      const float rfac = rsl[rl];
      float se = 0.f, ps = 0.f;
      #pragma unroll
      for (int ni = 0; ni < 4; ++ni) {
        const float s = (float)acc[mi][ni][r] * rfac * cfv[ni];
        const float e = __expf(s);
        const bool match = (ctv[ni] == rty);
        if (diag) {
          if (gcolv[ni] != grow) { se += e; if (match) ps += s; }
        } else {
          se += e; if (match) ps += s;
          cse[ni] += e; if (match) cps[ni] += s;
        }
      }
      #pragma unroll
      for (int m = 8; m; m >>= 1) {
        se += __shfl_xor(se, m);
        ps += __shfl_xor(ps, m);
      }
      if (csub == 0) {                     // LDS atomics (2-way: wc pair)
        atomicAdd(&s_se[rl], se);
        atomicAdd(&s_ps[rl], ps);
      }
    }
  }

  if (!diag) {
    #pragma unroll
    for (int ni = 0; ni < 4; ++ni) {
      float se = cse[ni], ps = cps[ni];
      se += __shfl_xor(se, 16); se += __shfl_xor(se, 32);
      ps += __shfl_xor(ps, 16); ps += __shfl_xor(ps, 32);
      if (lane < 16) {                     // LDS atomics (2-way: wr pair)
        const int cl = wc * 64 + ni * 16 + csub;
        atomicAdd(&s_cse[cl], se);
        atomicAdd(&s_cps[cl], ps);
      }
    }
  }
  __syncthreads();

  // one coalesced plain store per block: partial[tc][0..127]=row-side,
  // [128..255]=col-side (zeros for diag tiles).
  const int tc = rb * (rb + 1) / 2 + cb;   // canonical tile id
  float v1, v2;
  if (tid < 128) { v1 = s_se[tid];       v2 = s_ps[tid]; }
  else           { v1 = s_cse[tid - 128]; v2 = s_cps[tid - 128]; }
  pse[(size_t)tc * 256 + tid] = v1;
  pps[(size_t)tc * 256 + tid] = v2;
}

// gather partials -> per-row sums (plain stores, no atomics).
// row r: row-side tiles (rb, cb=0..rb) at [tc][rr]; col-side tiles
// (i=rb+1..63, rb) at [tc][128+rr]. Each lane handles one tile.
__global__ __launch_bounds__(256) void k_reduce(
    const float* __restrict__ pse, const float* __restrict__ pps,
    float* __restrict__ sum_exp, float* __restrict__ pos_sum) {
  const int r = blockIdx.x * 4 + (threadIdx.x >> 6);
  const int lane = threadIdx.x & 63;
  const int rb = r >> 7, rr = r & 127;
  float se = 0.f, ps = 0.f;
  if (lane <= rb) {
    const size_t idx = (size_t)(rb * (rb + 1) / 2 + lane) * 256 + rr;
    se += pse[idx]; ps += pps[idx];
  }
  const int i = rb + 1 + lane;
  if (i < 64) {
    const size_t idx = (size_t)(i * (i + 1) / 2 + rb) * 256 + 128 + rr;
    se += pse[idx]; ps += pps[idx];
  }
  #pragma unroll
  for (int m = 32; m; m >>= 1) {
    se += __shfl_xor(se, m);
    ps += __shfl_xor(ps, m);
  }
  if (lane == 0) { sum_exp[r] = se; pos_sum[r] = ps; }
}

__global__ __launch_bounds__(1024) void k_final(
    const float* __restrict__ sum_exp, const float* __restrict__ pos_sum,
    const int* __restrict__ types, float* __restrict__ out) {
  const int t = threadIdx.x;
  __shared__ int h[32];
  if (t < 32) h[t] = 0;
  __syncthreads();
  int ty[8];
  #pragma unroll
  for (int i = 0; i < 8; ++i) {
    ty[i] = types[t + i * 1024];
    atomicAdd(&h[ty[i]], 1);
  }
  __syncthreads();
  float ls = 0.f, cnt = 0.f;
  #pragma unroll
  for (int i = 0; i < 8; ++i) {
    const int r = t + i * 1024;
    const int pc = h[ty[i]] - 1;
    if (pc > 0) {
      const float pm = pos_sum[r] / (float)pc;
      ls += -logf(__expf(pm) / sum_exp[r] + 1e-10f);
      cnt += 1.f;
    }
  }
  #pragma unroll
  for (int m = 32; m; m >>= 1) {
    ls += __shfl_xor(ls, m);
    cnt += __shfl_xor(cnt, m);
  }
  __shared__ float s1[16], s2[16];
  if ((t & 63) == 0) { s1[t >> 6] = ls; s2[t >> 6] = cnt; }
  __syncthreads();
  if (t == 0) {
    float T = 0.f, C = 0.f;
    for (int i = 0; i < 16; ++i) { T += s1[i]; C += s2[i]; }
    out[0] = (C > 0.f) ? T / C : 0.f;
  }
}

extern "C" void kernel_launch(void* const* d_in, const int* in_sizes, int n_in,
                              void* d_out, int out_size, void* d_ws, size_t ws_size,
                              hipStream_t stream) {
  const float* feat = (const float*)d_in[0];
  const long long* et = (const long long*)d_in[1];
  char* ws = (char*)d_ws;
  signed char* q8 = (signed char*)(ws + OFF_Q8);
  float* pse    = (float*)(ws + OFF_PSE);
  float* pps    = (float*)(ws + OFF_PPS);
  float* sum_e  = (float*)(ws + OFF_SUME);
  float* pos_s  = (float*)(ws + OFF_POSS);
  int* types    = (int*)(ws + OFF_TYPE);
  float* scale  = (float*)(ws + OFF_SCALE);
  float* out    = (float*)d_out;

  k_norm<<<N / 4, 256, 0, stream>>>(feat, et, q8, scale, types);
  k_gemm<<<NTRI, 256, 0, stream>>>(q8, scale, types, pse, pps);
  k_reduce<<<N / 4, 256, 0, stream>>>(pse, pps, sum_e, pos_s);
  k_final<<<1, 1024, 0, stream>>>(sum_e, pos_s, types, out);
}